// Round 7
// baseline (33.686 us; speedup 1.0000x reference)
//
#include <hip/hip_runtime.h>

// BilateralFilter fp32, 8 images 512x512, 3x3, sigma=0.8.
// v7: block-cooperative LDS staging.
//  - block tile: 32 rows x 64 cols output; stages [5 planes][34][72] fp32
//    (zero-filled halos -> exact reference zero-pad semantics), 47.8 KB LDS.
//  - 15 coalesced float4 loads/thread, one barrier, then all compute reads
//    are LDS hits (no edge gathers, no global latency on the critical path).
//  - compute: R5's pair-symmetric 2x4-px core (center taps folded, H pairs
//    shared, V/diag pairs computed once for both endpoints).

constexpr int HH = 512, WW = 512, HW = HH * WW;
constexpr int TR = 32, TC = 64;        // output tile per block
constexpr int LR = TR + 2;             // 34 staged rows
constexpr int LC = TC + 8;             // 72 staged cols (cb-4 .. cb+67)
constexpr int PL = LR * LC;            // 2448 floats per plane
constexpr int NGRP = LR * (LC / 4);    // 612 float4 groups per plane

#define KEXP (-1.1271055f)             // -(1/(2*0.8^2)) * log2(e)
#define E2(x) __builtin_amdgcn_exp2f(x)
#define WS0f 0.2724967f                // normalized spatial gaussian, d2=0
#define WS1f 0.1247577f                // d2=1
#define WS2f 0.0571180f                // d2=2

__global__ __launch_bounds__(256, 3) void bilateral_v7(
    const float* __restrict__ depth,   // [N,1,H,W]
    const float* __restrict__ color,   // [N,3,H,W]
    const float* __restrict__ mask,    // [N,1,H,W]
    float* __restrict__ out)           // [N,3,H,W]
{
    __shared__ __align__(16) float lds[5 * PL];   // 48960 B

    const int tid = threadIdx.x;
    const int b   = blockIdx.x;
    const int n   = b >> 7;            // image 0..7   (128 blocks/image)
    const int rg  = (b >> 3) & 15;     // row group 0..15
    const int cg  = b & 7;             // col group 0..7
    const int rb  = rg * TR;
    const int cb  = cg * TC;

    const float* dptr = depth + (size_t)n * HW;
    const float* mptr = mask  + (size_t)n * HW;
    const float* xptr = color + (size_t)n * 3 * HW;
    const float* yptr = xptr + HW;
    const float* zptr = xptr + 2 * HW;

    // ---- Stage [5][34][72] with zero-filled halos ----
    {
        const float* planes[5] = { dptr, mptr, xptr, yptr, zptr };
        #pragma unroll
        for (int p = 0; p < 5; ++p) {
            const float* src = planes[p];
            #pragma unroll
            for (int k = 0; k < 3; ++k) {
                const int f = tid + k * 256;
                if (f < NGRP) {
                    const int row = f / 18;           // LC/4 == 18
                    const int grp = f - row * 18;
                    const int gr  = rb - 1 + row;     // -1 .. 512
                    const int gc  = cb - 4 + grp * 4; // cb-4 .. cb+68
                    float4 v = make_float4(0.f, 0.f, 0.f, 0.f);
                    if (((unsigned)gr < (unsigned)HH) &&
                        ((unsigned)gc < (unsigned)WW))
                        v = *reinterpret_cast<const float4*>(src + gr * WW + gc);
                    // lds col = row*72 + grp*4 == 4*f  (linear)
                    *reinterpret_cast<float4*>(&lds[p * PL + f * 4]) = v;
                }
            }
        }
    }
    __syncthreads();

    // ---- Compute: 2 rows x 4 cols per thread ----
    const int rp = tid >> 4;           // row-pair 0..15
    const int c4 = tid & 15;           // col-group 0..15
    const int lc = c4 * 4;             // local col 0..60
    const int lr = rp * 2;             // LDS row of (img rA - 1)

    // Window rows: cols 0..5 = w-1 .. w+4 (LDS cols lc+3 .. lc+8)
    float AD[6], AM[6], AX[6], AY[6], AZ[6];   // row rA     (LDS lr+1)
    float BD[6], BM[6], BX[6], BY[6], BZ[6];   // row rA+1   (LDS lr+2)
    float TD[6], TM[6], TX[6], TY[6], TZ[6];   // side row   (LDS lr, then lr+3)

#define RDW(W, p, row) do {                                                  \
    const float* _b = &lds[(p) * PL + (row) * LC + lc];                      \
    const float2 _e0 = *reinterpret_cast<const float2*>(_b + 2);             \
    const float4 _m  = *reinterpret_cast<const float4*>(_b + 4);             \
    const float2 _e1 = *reinterpret_cast<const float2*>(_b + 8);             \
    W[0] = _e0.y; W[1] = _m.x; W[2] = _m.y; W[3] = _m.z; W[4] = _m.w;        \
    W[5] = _e1.x;                                                            \
} while (0)

#define RDROW(D_, M_, X_, Y_, Z_, row) do {                                  \
    RDW(D_, 0, row); RDW(M_, 1, row); RDW(X_, 2, row);                       \
    RDW(Y_, 3, row); RDW(Z_, 4, row);                                        \
} while (0)

    float aSwd[4], aSwc[4], aSt[4], aS0[4], aS1[4], aS2[4];
    float bSwd[4], bSwc[4], bSt[4], bS0[4], bS1[4], bS2[4];
    #pragma unroll
    for (int i = 0; i < 4; ++i) {
        aSwd[i]=0.f; aSwc[i]=0.f; aSt[i]=0.f; aS0[i]=0.f; aS1[i]=0.f; aS2[i]=0.f;
        bSwd[i]=0.f; bSwc[i]=0.f; bSt[i]=0.f; bS0[i]=0.f; bS1[i]=0.f; bS2[i]=0.f;
    }

#define HPASS(D_, M_, X_, Y_, Z_, Swd, Swc, St, S0, S1, S2) do {             \
    float hwd[5], hwc[5];                                                    \
    _Pragma("unroll") for (int j = 0; j < 5; ++j) {                          \
        const float dd = D_[j] - D_[j + 1];                                  \
        hwd[j] = E2(KEXP * dd * dd);                                         \
        const float f0 = X_[j] - X_[j + 1];                                  \
        const float f1 = Y_[j] - Y_[j + 1];                                  \
        const float f2 = Z_[j] - Z_[j + 1];                                  \
        hwc[j] = E2(KEXP * f0 * f0) + E2(KEXP * f1 * f1)                     \
               + E2(KEXP * f2 * f2);                                         \
    }                                                                        \
    _Pragma("unroll") for (int i = 0; i < 4; ++i) {                          \
        const int ci = i + 1;                                                \
        { const float t = (3.0f * WS0f) * M_[ci];                            \
          Swd[i] += 1.0f; Swc[i] += 3.0f; St[i] += t;                        \
          S0[i] += t * X_[ci]; S1[i] += t * Y_[ci]; S2[i] += t * Z_[ci]; }   \
        { const float t = hwd[i] * hwc[i] * WS1f * M_[i];                    \
          Swd[i] += hwd[i]; Swc[i] += hwc[i]; St[i] += t;                    \
          S0[i] += t * X_[i]; S1[i] += t * Y_[i]; S2[i] += t * Z_[i]; }      \
        { const float t = hwd[i+1] * hwc[i+1] * WS1f * M_[i+2];              \
          Swd[i] += hwd[i+1]; Swc[i] += hwc[i+1]; St[i] += t;                \
          S0[i] += t * X_[i+2]; S1[i] += t * Y_[i+2]; S2[i] += t * Z_[i+2];} \
    }                                                                        \
} while (0)

#define SIDE(D_, M_, X_, Y_, Z_, RD, RX, RY, RZ, Swd, Swc, St, S0, S1, S2) do { \
    _Pragma("unroll") for (int i = 0; i < 4; ++i) {                          \
        const float cd = RD[i + 1];                                          \
        const float cx = RX[i + 1];                                          \
        const float cy = RY[i + 1];                                          \
        const float cz = RZ[i + 1];                                          \
        _Pragma("unroll") for (int dj = 0; dj < 3; ++dj) {                   \
            const int c = i + dj;                                            \
            const float dd = D_[c] - cd;                                     \
            const float wd = E2(KEXP * dd * dd);                             \
            const float f0 = X_[c] - cx;                                     \
            const float f1 = Y_[c] - cy;                                     \
            const float f2 = Z_[c] - cz;                                     \
            const float wc = E2(KEXP * f0 * f0) + E2(KEXP * f1 * f1)         \
                           + E2(KEXP * f2 * f2);                             \
            const float ws = (dj == 1) ? WS1f : WS2f;                        \
            const float t = wd * wc * ws * M_[c];                            \
            Swd[i] += wd; Swc[i] += wc; St[i] += t;                          \
            S0[i] += t * X_[c]; S1[i] += t * Y_[c]; S2[i] += t * Z_[c];      \
        }                                                                    \
    }                                                                        \
} while (0)

    RDROW(AD, AM, AX, AY, AZ, lr + 1);
    RDROW(BD, BM, BX, BY, BZ, lr + 2);
    RDROW(TD, TM, TX, TY, TZ, lr);         // top side row (zeros at image edge)

    HPASS(AD, AM, AX, AY, AZ, aSwd, aSwc, aSt, aS0, aS1, aS2);
    HPASS(BD, BM, BX, BY, BZ, bSwd, bSwc, bSt, bS0, bS1, bS2);

    SIDE(TD, TM, TX, TY, TZ, AD, AX, AY, AZ,
         aSwd, aSwc, aSt, aS0, aS1, aS2);

    RDROW(TD, TM, TX, TY, TZ, lr + 3);     // bottom side row (reuse T regs)

    // Vertical + diagonal pairs between rows A and B (computed once).
    #pragma unroll
    for (int a = 0; a < 6; ++a) {
        #pragma unroll
        for (int db = -1; db <= 1; ++db) {
            const int bb = a + db;
            if (bb < 0 || bb > 5) continue;
            const bool useA = (a >= 1 && a <= 4);
            const bool useB = (bb >= 1 && bb <= 4);
            if (!useA && !useB) continue;
            const float dd = AD[a] - BD[bb];
            const float pwd = E2(KEXP * dd * dd);
            const float f0 = AX[a] - BX[bb];
            const float f1 = AY[a] - BY[bb];
            const float f2 = AZ[a] - BZ[bb];
            const float pwc = E2(KEXP * f0 * f0) + E2(KEXP * f1 * f1)
                            + E2(KEXP * f2 * f2);
            const float g = pwd * pwc;
            const float ws = (db == 0) ? WS1f : WS2f;
            if (useA) {
                const int i = a - 1;
                const float t = g * ws * BM[bb];
                aSwd[i] += pwd; aSwc[i] += pwc; aSt[i] += t;
                aS0[i] += t * BX[bb]; aS1[i] += t * BY[bb]; aS2[i] += t * BZ[bb];
            }
            if (useB) {
                const int i = bb - 1;
                const float t = g * ws * AM[a];
                bSwd[i] += pwd; bSwc[i] += pwc; bSt[i] += t;
                bS0[i] += t * AX[a]; bS1[i] += t * AY[a]; bS2[i] += t * AZ[a];
            }
        }
    }

    SIDE(TD, TM, TX, TY, TZ, BD, BX, BY, BZ,
         bSwd, bSwc, bSt, bS0, bS1, bS2);

    // out = Stc / (St + 9e-7 * Swd * Swc)
    float oa0[4], oa1[4], oa2[4], ob0[4], ob1[4], ob2[4];
    #pragma unroll
    for (int i = 0; i < 4; ++i) {
        const float invA = __builtin_amdgcn_rcpf(aSt[i] + 9e-7f * aSwd[i] * aSwc[i]);
        oa0[i] = aS0[i] * invA; oa1[i] = aS1[i] * invA; oa2[i] = aS2[i] * invA;
        const float invB = __builtin_amdgcn_rcpf(bSt[i] + 9e-7f * bSwd[i] * bSwc[i]);
        ob0[i] = bS0[i] * invB; ob1[i] = bS1[i] * invB; ob2[i] = bS2[i] * invB;
    }

    const int orow = rb + rp * 2;
    const int ocol = cb + lc;
    float* po = out + (size_t)n * 3 * HW + orow * WW + ocol;
    *reinterpret_cast<float4*>(po)               = make_float4(oa0[0], oa0[1], oa0[2], oa0[3]);
    *reinterpret_cast<float4*>(po + HW)          = make_float4(oa1[0], oa1[1], oa1[2], oa1[3]);
    *reinterpret_cast<float4*>(po + 2 * HW)      = make_float4(oa2[0], oa2[1], oa2[2], oa2[3]);
    *reinterpret_cast<float4*>(po + WW)          = make_float4(ob0[0], ob0[1], ob0[2], ob0[3]);
    *reinterpret_cast<float4*>(po + WW + HW)     = make_float4(ob1[0], ob1[1], ob1[2], ob1[3]);
    *reinterpret_cast<float4*>(po + WW + 2 * HW) = make_float4(ob2[0], ob2[1], ob2[2], ob2[3]);
}

extern "C" void kernel_launch(void* const* d_in, const int* in_sizes, int n_in,
                              void* d_out, int out_size, void* d_ws, size_t ws_size,
                              hipStream_t stream) {
    const float* depth = (const float*)d_in[0];
    const float* color = (const float*)d_in[1];
    const float* mask  = (const float*)d_in[2];
    float* out = (float*)d_out;

    // 8 images x 16 row-groups x 8 col-groups = 1024 blocks
    bilateral_v7<<<1024, 256, 0, stream>>>(depth, color, mask, out);
}